// Round 6
// baseline (269.163 us; speedup 1.0000x reference)
//
#include <hip/hip_runtime.h>
#include <hip/hip_bf16.h>

typedef __attribute__((ext_vector_type(8)))  short bf16x8;
typedef __attribute__((ext_vector_type(4)))  float f32x4;
typedef __attribute__((ext_vector_type(16))) float f32x16;
typedef __attribute__((ext_vector_type(2)))  int   i32x2;

#define NH  16
#define HD  64
#define SEQ 2048
#define DM  1024   // NH*HD
#define NB  4

// Q pre-scale: 1/sqrt(64) * log2(e)  (softmax done in exp2 domain)
#define QSCALE 0.18033688011112042f

#define MFMA(a,b,c)   __builtin_amdgcn_mfma_f32_16x16x32_bf16((a),(b),(c),0,0,0)
#define MFMA32(a,b,c) __builtin_amdgcn_mfma_f32_32x32x16_bf16((a),(b),(c),0,0,0)

static __device__ __forceinline__ void gload_lds16(const void* g, void* l) {
    __builtin_amdgcn_global_load_lds(
        (const __attribute__((address_space(1))) void*)g,
        (__attribute__((address_space(3))) void*)l, 16, 0, 0);
}

// ---------------- cast float -> bf16, 4 elems/thread ----------------
__global__ void cast_f32_bf16(const float* __restrict__ src,
                              __hip_bfloat16* __restrict__ dst, long n) {
    long i = ((long)blockIdx.x * blockDim.x + threadIdx.x) * 4;
    if (i >= n) return;
    float4 v = *reinterpret_cast<const float4*>(src + i);
    ushort4 o;
    o.x = __bfloat16_as_ushort(__float2bfloat16(v.x));
    o.y = __bfloat16_as_ushort(__float2bfloat16(v.y));
    o.z = __bfloat16_as_ushort(__float2bfloat16(v.z));
    o.w = __bfloat16_as_ushort(__float2bfloat16(v.w));
    *reinterpret_cast<ushort4*>(dst + i) = o;
}

// ------------- transpose+cast [mats][R][C] f32 -> [mats][C][R] bf16 -------------
__global__ void transpose_cast_k(const float* __restrict__ src,
                                 __hip_bfloat16* __restrict__ dst,
                                 int mats, int R, int C) {
    long idx = (long)blockIdx.x * blockDim.x + threadIdx.x;
    long total = (long)mats * R * C;
    if (idx >= total) return;
    int c = (int)(idx % C);
    long t = idx / C;
    int r = (int)(t % R);
    int m = (int)(t / R);
    dst[((long)m * C + c) * R + r] = __float2bfloat16(src[idx]);
}

// ---------------- tiled GEMM: C[M][N] = A[M][1024] * BT[N][1024]^T ----------------
// 128x128 tile, BK=32, double-buffered LDS via global_load_lds(16B), XOR swizzle.
// MODE 0: qkv epilogue (N=3072 fused; z selects Q/K/V layout+bias, Q*=QSCALE)
// MODE 1: float-out epilogue with bias (out projection)
template<int MODE>
__global__ __launch_bounds__(256)
void gemm_bt(const __hip_bfloat16* __restrict__ A,
             const __hip_bfloat16* __restrict__ BT,
             const float* __restrict__ b0,
             const float* __restrict__ b1,
             const float* __restrict__ b2,
             __hip_bfloat16* __restrict__ Qo,
             __hip_bfloat16* __restrict__ Ko,
             __hip_bfloat16* __restrict__ Vto,
             float* __restrict__ Fo) {
    __shared__ __align__(16) char smem[2][16384];   // [buf][A:0..8191 | B:8192..16383]
    int tid = threadIdx.x;
    int w = tid >> 6, l = tid & 63;
    int wr = w >> 1, wc = w & 1;
    int lr = l & 15, lg = l >> 4;
    int mtile = blockIdx.x, ntile = blockIdx.y;

    const __hip_bfloat16* Ab = A  + (long)mtile * 128 * DM;
    const __hip_bfloat16* Bb = BT + (long)ntile * 128 * DM;

    const int srow0 = tid >> 2;
    const int srow1 = 64 + srow0;
    const int g0 = (tid & 3) ^ ((srow0 >> 1) & 3);

    int aoff[4], boff[4];
#pragma unroll
    for (int m = 0; m < 4; ++m) {
        int ra = wr * 64 + m * 16 + lr;
        aoff[m] = ra * 64 + ((lg ^ ((ra >> 1) & 3)) * 16);
        int rb = wc * 64 + m * 16 + lr;
        boff[m] = 8192 + rb * 64 + ((lg ^ ((rb >> 1) & 3)) * 16);
    }

    f32x4 acc[4][4] = {};

    {
        char* base = smem[0] + w * 1024;
        gload_lds16(Ab + (long)srow0 * DM + g0 * 8, base);
        gload_lds16(Ab + (long)srow1 * DM + g0 * 8, base + 4096);
        gload_lds16(Bb + (long)srow0 * DM + g0 * 8, base + 8192);
        gload_lds16(Bb + (long)srow1 * DM + g0 * 8, base + 12288);
    }
    __syncthreads();

    int cur = 0;
    for (int kt = 0; kt < 32; ++kt) {
        if (kt != 31) {
            int k0 = (kt + 1) * 32;
            char* base = smem[cur ^ 1] + w * 1024;
            gload_lds16(Ab + (long)srow0 * DM + k0 + g0 * 8, base);
            gload_lds16(Ab + (long)srow1 * DM + k0 + g0 * 8, base + 4096);
            gload_lds16(Bb + (long)srow0 * DM + k0 + g0 * 8, base + 8192);
            gload_lds16(Bb + (long)srow1 * DM + k0 + g0 * 8, base + 12288);
        }
        bf16x8 af[4], bf[4];
#pragma unroll
        for (int m = 0; m < 4; ++m)
            af[m] = *reinterpret_cast<const bf16x8*>(smem[cur] + aoff[m]);
#pragma unroll
        for (int n = 0; n < 4; ++n)
            bf[n] = *reinterpret_cast<const bf16x8*>(smem[cur] + boff[n]);
#pragma unroll
        for (int m = 0; m < 4; ++m)
#pragma unroll
            for (int n = 0; n < 4; ++n)
                acc[m][n] = MFMA(af[m], bf[n], acc[m][n]);
        __syncthreads();
        cur ^= 1;
    }

    if (MODE == 0) {
        int z = (ntile * 128) >> 10;
        const float* bias = (z == 0) ? b0 : (z == 1) ? b1 : b2;
        int colbase = (ntile * 128 + wc * 64) & 1023;
#pragma unroll
        for (int n = 0; n < 4; ++n) {
            int hc = colbase + n * 16 + lr;               // h*64+e
            int h = hc >> 6, e = hc & 63;
            float bb = bias[hc];
#pragma unroll
            for (int m = 0; m < 4; ++m) {
                int row0 = mtile * 128 + wr * 64 + m * 16 + lg * 4;
                int b = row0 >> 11, s0 = row0 & 2047;
                if (z == 0) {
#pragma unroll
                    for (int r = 0; r < 4; ++r)
                        Qo[(((long)b * NH + h) * SEQ + s0 + r) * HD + e] =
                            __float2bfloat16((acc[m][n][r] + bb) * QSCALE);
                } else if (z == 1) {
#pragma unroll
                    for (int r = 0; r < 4; ++r)
                        Ko[(((long)b * NH + h) * SEQ + s0 + r) * HD + e] =
                            __float2bfloat16(acc[m][n][r] + bb);
                } else {
                    ushort4 s4;
                    s4.x = __bfloat16_as_ushort(__float2bfloat16(acc[m][n][0] + bb));
                    s4.y = __bfloat16_as_ushort(__float2bfloat16(acc[m][n][1] + bb));
                    s4.z = __bfloat16_as_ushort(__float2bfloat16(acc[m][n][2] + bb));
                    s4.w = __bfloat16_as_ushort(__float2bfloat16(acc[m][n][3] + bb));
                    *reinterpret_cast<ushort4*>(
                        Vto + ((long)(b * NH + h) * HD + e) * SEQ + s0) = s4;
                }
            }
        }
    } else {
#pragma unroll
        for (int n = 0; n < 4; ++n) {
            int col = ntile * 128 + wc * 64 + n * 16 + lr;
            float bb = b0[col];
#pragma unroll
            for (int m = 0; m < 4; ++m) {
                long row0 = mtile * 128 + wr * 64 + m * 16 + lg * 4;
#pragma unroll
                for (int r = 0; r < 4; ++r)
                    Fo[(row0 + r) * DM + col] = acc[m][n][r] + bb;
            }
        }
    }
}

// ---------------- helpers for flash ----------------
static __device__ __forceinline__ unsigned pkbf(float a, float b) {
    __hip_bfloat162 h = __float22bfloat162_rn(float2{a, b});  // a -> low 16
    union { __hip_bfloat162 h2; unsigned u; } u_; u_.h2 = h;
    return u_.u;
}
static __device__ __forceinline__ bf16x8 make_pb(unsigned w0, unsigned w1,
                                                 unsigned w2, unsigned w3) {
    union { unsigned u[4]; bf16x8 v; } u_;
    u_.u[0] = w0; u_.u[1] = w1; u_.u[2] = w2; u_.u[3] = w3;
    return u_.v;
}
// v_permlane32_swap: r[0] = concat(a_lo, b_lo), r[1] = concat(a_hi, b_hi)
static __device__ __forceinline__ i32x2 pl32swap(unsigned a, unsigned b) {
    return __builtin_amdgcn_permlane32_swap((int)a, (int)b, false, false);
}
static __device__ __forceinline__ float xmax32(float x) {
    i32x2 r = pl32swap(__float_as_uint(x), __float_as_uint(x));
    return fmaxf(__uint_as_float((unsigned)r[0]), __uint_as_float((unsigned)r[1]));
}
static __device__ __forceinline__ float xsum32(float x) {
    i32x2 r = pl32swap(__float_as_uint(x), __float_as_uint(x));
    return __uint_as_float((unsigned)r[0]) + __uint_as_float((unsigned)r[1]);
}

// One kv-tile: QK^T (swapped), online softmax (exp2 domain, defer-max),
// P->bf16 B-frags via permlane32_swap, PV accumulate.
template<bool MASKED>
static __device__ __forceinline__ void attn_tile(
    const bf16x8* kf, const bf16x8* qf,
    bf16x8 v00, bf16x8 v10, bf16x8 v01, bf16x8 v11,
    int lo5, int hi,
    f32x16& o0, f32x16& o1, float& m, float& lsum) {
    f32x16 st = {};
    __builtin_amdgcn_s_setprio(1);
#pragma unroll
    for (int kd = 0; kd < 4; ++kd) st = MFMA32(kf[kd], qf[kd], st);
    __builtin_amdgcn_s_setprio(0);
    if (MASKED) {
#pragma unroll
        for (int r = 0; r < 16; ++r) {
            int kvloc = (r & 3) + 8 * (r >> 2) + 4 * hi;
            st[r] = (kvloc > lo5) ? -INFINITY : st[r];
        }
    }
    // tree max over 16 regs, then cross-half via permlane
    float t0 = fmaxf(st[0], st[1]),   t1 = fmaxf(st[2], st[3]);
    float t2 = fmaxf(st[4], st[5]),   t3 = fmaxf(st[6], st[7]);
    float t4 = fmaxf(st[8], st[9]),   t5 = fmaxf(st[10], st[11]);
    float t6 = fmaxf(st[12], st[13]), t7 = fmaxf(st[14], st[15]);
    t0 = fmaxf(t0, t1); t2 = fmaxf(t2, t3); t4 = fmaxf(t4, t5); t6 = fmaxf(t6, t7);
    float tm = xmax32(fmaxf(fmaxf(t0, t2), fmaxf(t4, t6)));
    if (!__all(tm <= m + 11.0f)) {          // defer-max: p bounded by 2^11
        float mnew = fmaxf(m, tm);
        float fac = __builtin_amdgcn_exp2f(m - mnew);
        lsum *= fac;
#pragma unroll
        for (int r = 0; r < 16; ++r) { o0[r] *= fac; o1[r] *= fac; }
        m = mnew;
    }
    float p[16];
#pragma unroll
    for (int r = 0; r < 16; ++r) p[r] = __builtin_amdgcn_exp2f(st[r] - m);
    float s0 = (p[0] + p[1]) + (p[2] + p[3]);
    float s1 = (p[4] + p[5]) + (p[6] + p[7]);
    float s2 = (p[8] + p[9]) + (p[10] + p[11]);
    float s3 = (p[12] + p[13]) + (p[14] + p[15]);
    lsum += xsum32((s0 + s1) + (s2 + s3));

    unsigned pk0 = pkbf(p[0],  p[1]),  pk1 = pkbf(p[2],  p[3]);
    unsigned pk2 = pkbf(p[4],  p[5]),  pk3 = pkbf(p[6],  p[7]);
    unsigned pk4 = pkbf(p[8],  p[9]),  pk5 = pkbf(p[10], p[11]);
    unsigned pk6 = pkbf(p[12], p[13]), pk7 = pkbf(p[14], p[15]);
    // pb0 words: w0=concat(pk0_lo,pk2_lo) w1=concat(pk1_lo,pk3_lo)
    //            w2=concat(pk0_hi,pk2_hi) w3=concat(pk1_hi,pk3_hi)
    i32x2 s02 = pl32swap(pk0, pk2);
    i32x2 s13 = pl32swap(pk1, pk3);
    i32x2 s46 = pl32swap(pk4, pk6);
    i32x2 s57 = pl32swap(pk5, pk7);
    bf16x8 pb0 = make_pb((unsigned)s02[0], (unsigned)s13[0],
                         (unsigned)s02[1], (unsigned)s13[1]);
    bf16x8 pb1 = make_pb((unsigned)s46[0], (unsigned)s57[0],
                         (unsigned)s46[1], (unsigned)s57[1]);

    __builtin_amdgcn_s_setprio(1);
    o0 = MFMA32(v00, pb0, o0);
    o1 = MFMA32(v10, pb0, o1);
    o0 = MFMA32(v01, pb1, o0);
    o1 = MFMA32(v11, pb1, o1);
    __builtin_amdgcn_s_setprio(0);
}

// ---------------- flash attention (causal, one q-tile per wave) ----------------
// Q (pre-scaled by QSCALE), K: [B,H,S,HD]; Vt: [B,H,HD,S]; O: [B*S][DM] (col h*64+d)
// Block's 4 waves: {p, 63-p, p+1, 62-p} -> 130 tile-computes per block (balanced).
__global__ __launch_bounds__(256)
void flash_attn(const __hip_bfloat16* __restrict__ Q,
                const __hip_bfloat16* __restrict__ K,
                const __hip_bfloat16* __restrict__ Vt,
                __hip_bfloat16* __restrict__ O) {
    int bh = blockIdx.x;                       // x=bh: same-head blocks share XCD
    int w  = threadIdx.x >> 6, l = threadIdx.x & 63;
    int lo5 = l & 31, hi = l >> 5;
    int pr = blockIdx.y * 2 + (w >> 1);        // pair index 0..31
    int j  = (w & 1) ? (63 - pr) : pr;         // q-tile for this wave
    int q0 = j * 32;

    const __hip_bfloat16* Qh = Q  + (long)bh * SEQ * HD;
    const __hip_bfloat16* Kh = K  + (long)bh * SEQ * HD;
    const __hip_bfloat16* Vh = Vt + (long)bh * HD * SEQ;   // [64][2048]

    bf16x8 qf[4];
#pragma unroll
    for (int kd = 0; kd < 4; ++kd)
        qf[kd] = *reinterpret_cast<const bf16x8*>(
            Qh + (long)(q0 + lo5) * HD + kd * 16 + hi * 8);

    f32x16 o0 = {}, o1 = {};
    float m = -INFINITY, lsum = 0.f;

    bf16x8 kf[4], kn[4];
#pragma unroll
    for (int kd = 0; kd < 4; ++kd)
        kf[kd] = *reinterpret_cast<const bf16x8*>(
            Kh + (long)(lo5) * HD + kd * 16 + hi * 8);

#define LOADK(T, DST)                                                      \
    _Pragma("unroll")                                                      \
    for (int kd = 0; kd < 4; ++kd)                                         \
        DST[kd] = *reinterpret_cast<const bf16x8*>(                        \
            Kh + (long)((T) * 32 + lo5) * HD + kd * 16 + hi * 8);

#define LOADV(KV0)                                                         \
    bf16x8 v00 = *reinterpret_cast<const bf16x8*>(                         \
        Vh + (long)(lo5) * SEQ + (KV0) + hi * 8);                          \
    bf16x8 v10 = *reinterpret_cast<const bf16x8*>(                         \
        Vh + (long)(32 + lo5) * SEQ + (KV0) + hi * 8);                     \
    bf16x8 v01 = *reinterpret_cast<const bf16x8*>(                         \
        Vh + (long)(lo5) * SEQ + (KV0) + 16 + hi * 8);                     \
    bf16x8 v11 = *reinterpret_cast<const bf16x8*>(                         \
        Vh + (long)(32 + lo5) * SEQ + (KV0) + 16 + hi * 8);

    for (int t = 0; t < j; ++t) {
        LOADK(t + 1, kn);
        LOADV(t * 32);
        attn_tile<false>(kf, qf, v00, v10, v01, v11, lo5, hi, o0, o1, m, lsum);
        kf[0] = kn[0]; kf[1] = kn[1]; kf[2] = kn[2]; kf[3] = kn[3];
    }
    {   // t = j: diagonal tile
        LOADV(j * 32);
        attn_tile<true>(kf, qf, v00, v10, v01, v11, lo5, hi, o0, o1, m, lsum);
    }
#undef LOADK
#undef LOADV

    int b = bh >> 4, h = bh & 15;
    float inv = 1.0f / lsum;
    __hip_bfloat16* orow = O + ((long)b * SEQ + q0 + lo5) * DM + h * HD;
#pragma unroll
    for (int nd = 0; nd < 2; ++nd) {
#pragma unroll
        for (int rg = 0; rg < 4; ++rg) {
            ushort4 s4;
            float a0 = (nd ? o1[rg * 4 + 0] : o0[rg * 4 + 0]) * inv;
            float a1 = (nd ? o1[rg * 4 + 1] : o0[rg * 4 + 1]) * inv;
            float a2 = (nd ? o1[rg * 4 + 2] : o0[rg * 4 + 2]) * inv;
            float a3 = (nd ? o1[rg * 4 + 3] : o0[rg * 4 + 3]) * inv;
            s4.x = __bfloat16_as_ushort(__float2bfloat16(a0));
            s4.y = __bfloat16_as_ushort(__float2bfloat16(a1));
            s4.z = __bfloat16_as_ushort(__float2bfloat16(a2));
            s4.w = __bfloat16_as_ushort(__float2bfloat16(a3));
            *reinterpret_cast<ushort4*>(orow + nd * 32 + rg * 8 + hi * 4) = s4;
        }
    }
}

extern "C" void kernel_launch(void* const* d_in, const int* in_sizes, int n_in,
                              void* d_out, int out_size, void* d_ws, size_t ws_size,
                              hipStream_t stream) {
    const float* x  = (const float*)d_in[0];
    const float* Wq = (const float*)d_in[1];
    const float* bq = (const float*)d_in[2];
    const float* Wk = (const float*)d_in[3];
    const float* bk = (const float*)d_in[4];
    const float* Wv = (const float*)d_in[5];
    const float* bv = (const float*)d_in[6];
    const float* Wp = (const float*)d_in[7];
    const float* bp = (const float*)d_in[8];
    float* out = (float*)d_out;

    char* ws = (char*)d_ws;
    const long XE = (long)NB * SEQ * DM;                 // 8,388,608
    const long QKV_ELEMS = (long)NB * NH * SEQ * HD;     // 8,388,608
    __hip_bfloat16* xb   = (__hip_bfloat16*)ws; ws += XE * 2;
    __hip_bfloat16* Qws  = (__hip_bfloat16*)ws; ws += QKV_ELEMS * 2;
    __hip_bfloat16* Kws  = (__hip_bfloat16*)ws; ws += QKV_ELEMS * 2;
    __hip_bfloat16* Vtws = (__hip_bfloat16*)ws; ws += QKV_ELEMS * 2;
    __hip_bfloat16* Ows  = (__hip_bfloat16*)ws; ws += QKV_ELEMS * 2;
    // fused WT[3072][1024]: rows 0-1023 = Wq^T, 1024-2047 = Wk^T, 2048-3071 = Wv^T
    __hip_bfloat16* wqt  = (__hip_bfloat16*)ws; ws += (long)NH * DM * HD * 2;
    __hip_bfloat16* wkt  = (__hip_bfloat16*)ws; ws += (long)NH * DM * HD * 2;
    __hip_bfloat16* wvt  = (__hip_bfloat16*)ws; ws += (long)NH * DM * HD * 2;
    __hip_bfloat16* wpt  = (__hip_bfloat16*)ws; ws += (long)DM * DM * 2;

    cast_f32_bf16<<<(int)(XE / 4 / 256), 256, 0, stream>>>(x, xb, XE);

    {
        long tot = (long)NH * DM * HD;
        int blks = (int)((tot + 255) / 256);
        transpose_cast_k<<<blks, 256, 0, stream>>>(Wq, wqt, NH, DM, HD);
        transpose_cast_k<<<blks, 256, 0, stream>>>(Wk, wkt, NH, DM, HD);
        transpose_cast_k<<<blks, 256, 0, stream>>>(Wv, wvt, NH, DM, HD);
        long tot2 = (long)DM * DM;
        transpose_cast_k<<<(int)((tot2 + 255) / 256), 256, 0, stream>>>(Wp, wpt, 1, DM, DM);
    }

    gemm_bt<0><<<dim3(64, 24), 256, 0, stream>>>(
        xb, wqt, bq, bk, bv, Qws, Kws, Vtws, nullptr);

    flash_attn<<<dim3(64, 16), 256, 0, stream>>>(Qws, Kws, Vtws, Ows);

    gemm_bt<1><<<dim3(64, 8), 256, 0, stream>>>(
        Ows, wpt, bp, nullptr, nullptr, nullptr, nullptr, nullptr, out);
}

// Round 7
// 244.548 us; speedup vs baseline: 1.1007x; 1.1007x over previous
//
#include <hip/hip_runtime.h>
#include <hip/hip_bf16.h>

typedef __attribute__((ext_vector_type(8)))  short bf16x8;
typedef __attribute__((ext_vector_type(4)))  float f32x4;
typedef __attribute__((ext_vector_type(16))) float f32x16;
typedef __attribute__((ext_vector_type(2)))  int   i32x2;

#define NH  16
#define HD  64
#define SEQ 2048
#define DM  1024   // NH*HD
#define NB  4

// Q pre-scale: 1/sqrt(64) * log2(e)  (softmax done in exp2 domain)
#define QSCALE 0.18033688011112042f

#define MFMA(a,b,c)   __builtin_amdgcn_mfma_f32_16x16x32_bf16((a),(b),(c),0,0,0)
#define MFMA32(a,b,c) __builtin_amdgcn_mfma_f32_32x32x16_bf16((a),(b),(c),0,0,0)

static __device__ __forceinline__ void gload_lds16(const void* g, void* l) {
    __builtin_amdgcn_global_load_lds(
        (const __attribute__((address_space(1))) void*)g,
        (__attribute__((address_space(3))) void*)l, 16, 0, 0);
}

// ---------------- cast float -> bf16, 4 elems/thread ----------------
__global__ void cast_f32_bf16(const float* __restrict__ src,
                              __hip_bfloat16* __restrict__ dst, long n) {
    long i = ((long)blockIdx.x * blockDim.x + threadIdx.x) * 4;
    if (i >= n) return;
    float4 v = *reinterpret_cast<const float4*>(src + i);
    ushort4 o;
    o.x = __bfloat16_as_ushort(__float2bfloat16(v.x));
    o.y = __bfloat16_as_ushort(__float2bfloat16(v.y));
    o.z = __bfloat16_as_ushort(__float2bfloat16(v.z));
    o.w = __bfloat16_as_ushort(__float2bfloat16(v.w));
    *reinterpret_cast<ushort4*>(dst + i) = o;
}

// ------------- transpose+cast [mats][R][C] f32 -> [mats][C][R] bf16 -------------
__global__ void transpose_cast_k(const float* __restrict__ src,
                                 __hip_bfloat16* __restrict__ dst,
                                 int mats, int R, int C) {
    long idx = (long)blockIdx.x * blockDim.x + threadIdx.x;
    long total = (long)mats * R * C;
    if (idx >= total) return;
    int c = (int)(idx % C);
    long t = idx / C;
    int r = (int)(t % R);
    int m = (int)(t / R);
    dst[((long)m * C + c) * R + r] = __float2bfloat16(src[idx]);
}

// ---------------- tiled GEMM: C[M][N] = A[M][1024] * BT[N][1024]^T ----------------
// 128x128 tile, BK=32, double-buffered LDS via global_load_lds(16B), XOR swizzle.
// MODE 0: qkv epilogue (N=3072 fused; z selects Q/K/V layout+bias, Q*=QSCALE)
// MODE 1: float-out epilogue with bias (out projection)
template<int MODE>
__global__ __launch_bounds__(256)
void gemm_bt(const __hip_bfloat16* __restrict__ A,
             const __hip_bfloat16* __restrict__ BT,
             const float* __restrict__ b0,
             const float* __restrict__ b1,
             const float* __restrict__ b2,
             __hip_bfloat16* __restrict__ Qo,
             __hip_bfloat16* __restrict__ Ko,
             __hip_bfloat16* __restrict__ Vto,
             float* __restrict__ Fo) {
    __shared__ __align__(16) char smem[2][16384];   // [buf][A:0..8191 | B:8192..16383]
    int tid = threadIdx.x;
    int w = tid >> 6, l = tid & 63;
    int wr = w >> 1, wc = w & 1;
    int lr = l & 15, lg = l >> 4;
    int mtile = blockIdx.x, ntile = blockIdx.y;

    const __hip_bfloat16* Ab = A  + (long)mtile * 128 * DM;
    const __hip_bfloat16* Bb = BT + (long)ntile * 128 * DM;

    const int srow0 = tid >> 2;
    const int srow1 = 64 + srow0;
    const int g0 = (tid & 3) ^ ((srow0 >> 1) & 3);

    int aoff[4], boff[4];
#pragma unroll
    for (int m = 0; m < 4; ++m) {
        int ra = wr * 64 + m * 16 + lr;
        aoff[m] = ra * 64 + ((lg ^ ((ra >> 1) & 3)) * 16);
        int rb = wc * 64 + m * 16 + lr;
        boff[m] = 8192 + rb * 64 + ((lg ^ ((rb >> 1) & 3)) * 16);
    }

    f32x4 acc[4][4] = {};

    {
        char* base = smem[0] + w * 1024;
        gload_lds16(Ab + (long)srow0 * DM + g0 * 8, base);
        gload_lds16(Ab + (long)srow1 * DM + g0 * 8, base + 4096);
        gload_lds16(Bb + (long)srow0 * DM + g0 * 8, base + 8192);
        gload_lds16(Bb + (long)srow1 * DM + g0 * 8, base + 12288);
    }
    __syncthreads();

    int cur = 0;
    for (int kt = 0; kt < 32; ++kt) {
        if (kt != 31) {
            int k0 = (kt + 1) * 32;
            char* base = smem[cur ^ 1] + w * 1024;
            gload_lds16(Ab + (long)srow0 * DM + k0 + g0 * 8, base);
            gload_lds16(Ab + (long)srow1 * DM + k0 + g0 * 8, base + 4096);
            gload_lds16(Bb + (long)srow0 * DM + k0 + g0 * 8, base + 8192);
            gload_lds16(Bb + (long)srow1 * DM + k0 + g0 * 8, base + 12288);
        }
        bf16x8 af[4], bf[4];
#pragma unroll
        for (int m = 0; m < 4; ++m)
            af[m] = *reinterpret_cast<const bf16x8*>(smem[cur] + aoff[m]);
#pragma unroll
        for (int n = 0; n < 4; ++n)
            bf[n] = *reinterpret_cast<const bf16x8*>(smem[cur] + boff[n]);
#pragma unroll
        for (int m = 0; m < 4; ++m)
#pragma unroll
            for (int n = 0; n < 4; ++n)
                acc[m][n] = MFMA(af[m], bf[n], acc[m][n]);
        __syncthreads();
        cur ^= 1;
    }

    if (MODE == 0) {
        int z = (ntile * 128) >> 10;
        const float* bias = (z == 0) ? b0 : (z == 1) ? b1 : b2;
        int colbase = (ntile * 128 + wc * 64) & 1023;
#pragma unroll
        for (int n = 0; n < 4; ++n) {
            int hc = colbase + n * 16 + lr;               // h*64+e
            int h = hc >> 6, e = hc & 63;
            float bb = bias[hc];
#pragma unroll
            for (int m = 0; m < 4; ++m) {
                int row0 = mtile * 128 + wr * 64 + m * 16 + lg * 4;
                int b = row0 >> 11, s0 = row0 & 2047;
                if (z == 0) {
#pragma unroll
                    for (int r = 0; r < 4; ++r)
                        Qo[(((long)b * NH + h) * SEQ + s0 + r) * HD + e] =
                            __float2bfloat16((acc[m][n][r] + bb) * QSCALE);
                } else if (z == 1) {
#pragma unroll
                    for (int r = 0; r < 4; ++r)
                        Ko[(((long)b * NH + h) * SEQ + s0 + r) * HD + e] =
                            __float2bfloat16(acc[m][n][r] + bb);
                } else {
                    ushort4 s4;
                    s4.x = __bfloat16_as_ushort(__float2bfloat16(acc[m][n][0] + bb));
                    s4.y = __bfloat16_as_ushort(__float2bfloat16(acc[m][n][1] + bb));
                    s4.z = __bfloat16_as_ushort(__float2bfloat16(acc[m][n][2] + bb));
                    s4.w = __bfloat16_as_ushort(__float2bfloat16(acc[m][n][3] + bb));
                    *reinterpret_cast<ushort4*>(
                        Vto + ((long)(b * NH + h) * HD + e) * SEQ + s0) = s4;
                }
            }
        }
    } else {
#pragma unroll
        for (int n = 0; n < 4; ++n) {
            int col = ntile * 128 + wc * 64 + n * 16 + lr;
            float bb = b0[col];
#pragma unroll
            for (int m = 0; m < 4; ++m) {
                long row0 = mtile * 128 + wr * 64 + m * 16 + lg * 4;
#pragma unroll
                for (int r = 0; r < 4; ++r)
                    Fo[(row0 + r) * DM + col] = acc[m][n][r] + bb;
            }
        }
    }
}

// ---------------- helpers for flash ----------------
static __device__ __forceinline__ unsigned pkbf(float a, float b) {
    __hip_bfloat162 h = __float22bfloat162_rn(float2{a, b});  // a -> low 16
    union { __hip_bfloat162 h2; unsigned u; } u_; u_.h2 = h;
    return u_.u;
}
static __device__ __forceinline__ bf16x8 make_pb(unsigned w0, unsigned w1,
                                                 unsigned w2, unsigned w3) {
    union { unsigned u[4]; bf16x8 v; } u_;
    u_.u[0] = w0; u_.u[1] = w1; u_.u[2] = w2; u_.u[3] = w3;
    return u_.v;
}
// v_permlane32_swap: r[0] = concat(a_lo, b_lo), r[1] = concat(a_hi, b_hi)
static __device__ __forceinline__ i32x2 pl32swap(unsigned a, unsigned b) {
    return __builtin_amdgcn_permlane32_swap((int)a, (int)b, false, false);
}
static __device__ __forceinline__ float xmax32(float x) {
    i32x2 r = pl32swap(__float_as_uint(x), __float_as_uint(x));
    return fmaxf(__uint_as_float((unsigned)r[0]), __uint_as_float((unsigned)r[1]));
}
static __device__ __forceinline__ float xsum32(float x) {
    i32x2 r = pl32swap(__float_as_uint(x), __float_as_uint(x));
    return __uint_as_float((unsigned)r[0]) + __uint_as_float((unsigned)r[1]);
}

// One kv-tile of one chain: QK^T (swapped), online softmax (exp2 domain,
// defer-max), P->bf16 B-frags via permlane32_swap, PV accumulate.
template<bool MASKED>
static __device__ __forceinline__ void attn_tile(
    const bf16x8* kf, const bf16x8* qf,
    bf16x8 v00, bf16x8 v10, bf16x8 v01, bf16x8 v11,
    int lo5, int hi,
    f32x16& o0, f32x16& o1, float& m, float& lsum) {
    f32x16 st = {};
    __builtin_amdgcn_s_setprio(1);
#pragma unroll
    for (int kd = 0; kd < 4; ++kd) st = MFMA32(kf[kd], qf[kd], st);
    __builtin_amdgcn_s_setprio(0);
    if (MASKED) {
#pragma unroll
        for (int r = 0; r < 16; ++r) {
            int kvloc = (r & 3) + 8 * (r >> 2) + 4 * hi;
            st[r] = (kvloc > lo5) ? -INFINITY : st[r];
        }
    }
    // tree max over 16 regs, then cross-half via permlane
    float t0 = fmaxf(st[0], st[1]),   t1 = fmaxf(st[2], st[3]);
    float t2 = fmaxf(st[4], st[5]),   t3 = fmaxf(st[6], st[7]);
    float t4 = fmaxf(st[8], st[9]),   t5 = fmaxf(st[10], st[11]);
    float t6 = fmaxf(st[12], st[13]), t7 = fmaxf(st[14], st[15]);
    t0 = fmaxf(t0, t1); t2 = fmaxf(t2, t3); t4 = fmaxf(t4, t5); t6 = fmaxf(t6, t7);
    float tm = xmax32(fmaxf(fmaxf(t0, t2), fmaxf(t4, t6)));
    if (!__all(tm <= m + 11.0f)) {          // defer-max: p bounded by 2^11
        float mnew = fmaxf(m, tm);
        float fac = __builtin_amdgcn_exp2f(m - mnew);
        lsum *= fac;
#pragma unroll
        for (int r = 0; r < 16; ++r) { o0[r] *= fac; o1[r] *= fac; }
        m = mnew;
    }
    float p[16];
#pragma unroll
    for (int r = 0; r < 16; ++r) p[r] = __builtin_amdgcn_exp2f(st[r] - m);
    float s0 = (p[0] + p[1]) + (p[2] + p[3]);
    float s1 = (p[4] + p[5]) + (p[6] + p[7]);
    float s2 = (p[8] + p[9]) + (p[10] + p[11]);
    float s3 = (p[12] + p[13]) + (p[14] + p[15]);
    lsum += xsum32((s0 + s1) + (s2 + s3));

    unsigned pk0 = pkbf(p[0],  p[1]),  pk1 = pkbf(p[2],  p[3]);
    unsigned pk2 = pkbf(p[4],  p[5]),  pk3 = pkbf(p[6],  p[7]);
    unsigned pk4 = pkbf(p[8],  p[9]),  pk5 = pkbf(p[10], p[11]);
    unsigned pk6 = pkbf(p[12], p[13]), pk7 = pkbf(p[14], p[15]);
    i32x2 s02 = pl32swap(pk0, pk2);
    i32x2 s13 = pl32swap(pk1, pk3);
    i32x2 s46 = pl32swap(pk4, pk6);
    i32x2 s57 = pl32swap(pk5, pk7);
    bf16x8 pb0 = make_pb((unsigned)s02[0], (unsigned)s13[0],
                         (unsigned)s02[1], (unsigned)s13[1]);
    bf16x8 pb1 = make_pb((unsigned)s46[0], (unsigned)s57[0],
                         (unsigned)s46[1], (unsigned)s57[1]);

    __builtin_amdgcn_s_setprio(1);
    o0 = MFMA32(v00, pb0, o0);
    o1 = MFMA32(v10, pb0, o1);
    o0 = MFMA32(v01, pb1, o0);
    o1 = MFMA32(v11, pb1, o1);
    __builtin_amdgcn_s_setprio(0);
}

// ---------------- flash attention (causal, paired antidiagonal waves) ----------------
// Q (pre-scaled by QSCALE), K: [B,H,S,HD]; Vt: [B,H,HD,S]; O: [B*S][DM] (col h*64+d)
// Wave handles q-tiles jA=pair and jB=63-pair: 65 tile-computes each (balanced),
// shared K/V loads, 2 independent chains for ILP, K prefetched one tile ahead.
__global__ __launch_bounds__(256)
void flash_attn(const __hip_bfloat16* __restrict__ Q,
                const __hip_bfloat16* __restrict__ K,
                const __hip_bfloat16* __restrict__ Vt,
                __hip_bfloat16* __restrict__ O) {
    int bh = blockIdx.x;                       // x=bh: same-head blocks share XCD
    int w  = threadIdx.x >> 6, l = threadIdx.x & 63;
    int lo5 = l & 31, hi = l >> 5;
    int pair = blockIdx.y * 4 + w;             // 0..31
    int jA = pair, jB = 63 - pair;
    int q0A = jA * 32, q0B = jB * 32;

    const __hip_bfloat16* Qh = Q  + (long)bh * SEQ * HD;
    const __hip_bfloat16* Kh = K  + (long)bh * SEQ * HD;
    const __hip_bfloat16* Vh = Vt + (long)bh * HD * SEQ;   // [64][2048]

    bf16x8 qfA[4], qfB[4];
#pragma unroll
    for (int kd = 0; kd < 4; ++kd) {
        qfA[kd] = *reinterpret_cast<const bf16x8*>(
            Qh + (long)(q0A + lo5) * HD + kd * 16 + hi * 8);
        qfB[kd] = *reinterpret_cast<const bf16x8*>(
            Qh + (long)(q0B + lo5) * HD + kd * 16 + hi * 8);
    }

    f32x16 oA0 = {}, oA1 = {}, oB0 = {}, oB1 = {};
    float mA = -INFINITY, lsA = 0.f, mB = -INFINITY, lsB = 0.f;

    bf16x8 kf[4], kn[4];
#pragma unroll
    for (int kd = 0; kd < 4; ++kd)
        kf[kd] = *reinterpret_cast<const bf16x8*>(
            Kh + (long)(lo5) * HD + kd * 16 + hi * 8);

#define LOADK(T, DST)                                                      \
    _Pragma("unroll")                                                      \
    for (int kd = 0; kd < 4; ++kd)                                         \
        DST[kd] = *reinterpret_cast<const bf16x8*>(                        \
            Kh + (long)((T) * 32 + lo5) * HD + kd * 16 + hi * 8);

#define LOADV(KV0)                                                         \
    bf16x8 v00 = *reinterpret_cast<const bf16x8*>(                         \
        Vh + (long)(lo5) * SEQ + (KV0) + hi * 8);                          \
    bf16x8 v10 = *reinterpret_cast<const bf16x8*>(                         \
        Vh + (long)(32 + lo5) * SEQ + (KV0) + hi * 8);                     \
    bf16x8 v01 = *reinterpret_cast<const bf16x8*>(                         \
        Vh + (long)(lo5) * SEQ + (KV0) + 16 + hi * 8);                     \
    bf16x8 v11 = *reinterpret_cast<const bf16x8*>(                         \
        Vh + (long)(32 + lo5) * SEQ + (KV0) + 16 + hi * 8);

    for (int t = 0; t < jA; ++t) {
        LOADK(t + 1, kn);
        LOADV(t * 32);
        attn_tile<false>(kf, qfB, v00, v10, v01, v11, lo5, hi, oB0, oB1, mB, lsB);
        attn_tile<false>(kf, qfA, v00, v10, v01, v11, lo5, hi, oA0, oA1, mA, lsA);
        kf[0] = kn[0]; kf[1] = kn[1]; kf[2] = kn[2]; kf[3] = kn[3];
    }
    {   // t = jA: A's diagonal
        LOADK(jA + 1, kn);
        LOADV(jA * 32);
        attn_tile<true >(kf, qfA, v00, v10, v01, v11, lo5, hi, oA0, oA1, mA, lsA);
        attn_tile<false>(kf, qfB, v00, v10, v01, v11, lo5, hi, oB0, oB1, mB, lsB);
        kf[0] = kn[0]; kf[1] = kn[1]; kf[2] = kn[2]; kf[3] = kn[3];
    }
    for (int t = jA + 1; t < jB; ++t) {
        LOADK(t + 1, kn);
        LOADV(t * 32);
        attn_tile<false>(kf, qfB, v00, v10, v01, v11, lo5, hi, oB0, oB1, mB, lsB);
        kf[0] = kn[0]; kf[1] = kn[1]; kf[2] = kn[2]; kf[3] = kn[3];
    }
    {   // t = jB: B's diagonal
        LOADV(jB * 32);
        attn_tile<true >(kf, qfB, v00, v10, v01, v11, lo5, hi, oB0, oB1, mB, lsB);
    }
#undef LOADK
#undef LOADV

    int b = bh >> 4, h = bh & 15;
#pragma unroll
    for (int c = 0; c < 2; ++c) {
        int q0 = c ? q0B : q0A;
        const f32x16& o0 = c ? oB0 : oA0;
        const f32x16& o1 = c ? oB1 : oA1;
        float inv = 1.0f / (c ? lsB : lsA);
        __hip_bfloat16* orow = O + ((long)b * SEQ + q0 + lo5) * DM + h * HD;
#pragma unroll
        for (int nd = 0; nd < 2; ++nd) {
#pragma unroll
            for (int rg = 0; rg < 4; ++rg) {
                ushort4 s4;
                float a0 = (nd ? o1[rg * 4 + 0] : o0[rg * 4 + 0]) * inv;
                float a1 = (nd ? o1[rg * 4 + 1] : o0[rg * 4 + 1]) * inv;
                float a2 = (nd ? o1[rg * 4 + 2] : o0[rg * 4 + 2]) * inv;
                float a3 = (nd ? o1[rg * 4 + 3] : o0[rg * 4 + 3]) * inv;
                s4.x = __bfloat16_as_ushort(__float2bfloat16(a0));
                s4.y = __bfloat16_as_ushort(__float2bfloat16(a1));
                s4.z = __bfloat16_as_ushort(__float2bfloat16(a2));
                s4.w = __bfloat16_as_ushort(__float2bfloat16(a3));
                *reinterpret_cast<ushort4*>(orow + nd * 32 + rg * 8 + hi * 4) = s4;
            }
        }
    }
}

extern "C" void kernel_launch(void* const* d_in, const int* in_sizes, int n_in,
                              void* d_out, int out_size, void* d_ws, size_t ws_size,
                              hipStream_t stream) {
    const float* x  = (const float*)d_in[0];
    const float* Wq = (const float*)d_in[1];
    const float* bq = (const float*)d_in[2];
    const float* Wk = (const float*)d_in[3];
    const float* bk = (const float*)d_in[4];
    const float* Wv = (const float*)d_in[5];
    const float* bv = (const float*)d_in[6];
    const float* Wp = (const float*)d_in[7];
    const float* bp = (const float*)d_in[8];
    float* out = (float*)d_out;

    char* ws = (char*)d_ws;
    const long XE = (long)NB * SEQ * DM;                 // 8,388,608
    const long QKV_ELEMS = (long)NB * NH * SEQ * HD;     // 8,388,608
    __hip_bfloat16* xb   = (__hip_bfloat16*)ws; ws += XE * 2;
    __hip_bfloat16* Qws  = (__hip_bfloat16*)ws; ws += QKV_ELEMS * 2;
    __hip_bfloat16* Kws  = (__hip_bfloat16*)ws; ws += QKV_ELEMS * 2;
    __hip_bfloat16* Vtws = (__hip_bfloat16*)ws; ws += QKV_ELEMS * 2;
    __hip_bfloat16* Ows  = (__hip_bfloat16*)ws; ws += QKV_ELEMS * 2;
    // fused WT[3072][1024]: rows 0-1023 = Wq^T, 1024-2047 = Wk^T, 2048-3071 = Wv^T
    __hip_bfloat16* wqt  = (__hip_bfloat16*)ws; ws += (long)NH * DM * HD * 2;
    __hip_bfloat16* wkt  = (__hip_bfloat16*)ws; ws += (long)NH * DM * HD * 2;
    __hip_bfloat16* wvt  = (__hip_bfloat16*)ws; ws += (long)NH * DM * HD * 2;
    __hip_bfloat16* wpt  = (__hip_bfloat16*)ws; ws += (long)DM * DM * 2;

    cast_f32_bf16<<<(int)(XE / 4 / 256), 256, 0, stream>>>(x, xb, XE);

    {
        long tot = (long)NH * DM * HD;
        int blks = (int)((tot + 255) / 256);
        transpose_cast_k<<<blks, 256, 0, stream>>>(Wq, wqt, NH, DM, HD);
        transpose_cast_k<<<blks, 256, 0, stream>>>(Wk, wkt, NH, DM, HD);
        transpose_cast_k<<<blks, 256, 0, stream>>>(Wv, wvt, NH, DM, HD);
        long tot2 = (long)DM * DM;
        transpose_cast_k<<<(int)((tot2 + 255) / 256), 256, 0, stream>>>(Wp, wpt, 1, DM, DM);
    }

    gemm_bt<0><<<dim3(64, 24), 256, 0, stream>>>(
        xb, wqt, bq, bk, bv, Qws, Kws, Vtws, nullptr);

    flash_attn<<<dim3(64, 8), 256, 0, stream>>>(Qws, Kws, Vtws, Ows);

    gemm_bt<1><<<dim3(64, 8), 256, 0, stream>>>(
        Ows, wpt, bp, nullptr, nullptr, nullptr, nullptr, nullptr, out);
}

// Round 8
// 239.370 us; speedup vs baseline: 1.1245x; 1.0216x over previous
//
#include <hip/hip_runtime.h>
#include <hip/hip_bf16.h>

typedef __attribute__((ext_vector_type(8)))  short bf16x8;
typedef __attribute__((ext_vector_type(4)))  float f32x4;
typedef __attribute__((ext_vector_type(16))) float f32x16;
typedef __attribute__((ext_vector_type(2)))  int   i32x2;

#define NH  16
#define HD  64
#define SEQ 2048
#define DM  1024   // NH*HD
#define NB  4

// Q pre-scale: 1/sqrt(64) * log2(e)  (softmax done in exp2 domain)
#define QSCALE 0.18033688011112042f

#define MFMA(a,b,c)   __builtin_amdgcn_mfma_f32_16x16x32_bf16((a),(b),(c),0,0,0)
#define MFMA32(a,b,c) __builtin_amdgcn_mfma_f32_32x32x16_bf16((a),(b),(c),0,0,0)

static __device__ __forceinline__ void gload_lds16(const void* g, void* l) {
    __builtin_amdgcn_global_load_lds(
        (const __attribute__((address_space(1))) void*)g,
        (__attribute__((address_space(3))) void*)l, 16, 0, 0);
}

// ---------------- cast float -> bf16, 4 elems/thread ----------------
__global__ void cast_f32_bf16(const float* __restrict__ src,
                              __hip_bfloat16* __restrict__ dst, long n) {
    long i = ((long)blockIdx.x * blockDim.x + threadIdx.x) * 4;
    if (i >= n) return;
    float4 v = *reinterpret_cast<const float4*>(src + i);
    ushort4 o;
    o.x = __bfloat16_as_ushort(__float2bfloat16(v.x));
    o.y = __bfloat16_as_ushort(__float2bfloat16(v.y));
    o.z = __bfloat16_as_ushort(__float2bfloat16(v.z));
    o.w = __bfloat16_as_ushort(__float2bfloat16(v.w));
    *reinterpret_cast<ushort4*>(dst + i) = o;
}

// ------------- transpose+cast [mats][R][C] f32 -> [mats][C][R] bf16 -------------
__global__ void transpose_cast_k(const float* __restrict__ src,
                                 __hip_bfloat16* __restrict__ dst,
                                 int mats, int R, int C) {
    long idx = (long)blockIdx.x * blockDim.x + threadIdx.x;
    long total = (long)mats * R * C;
    if (idx >= total) return;
    int c = (int)(idx % C);
    long t = idx / C;
    int r = (int)(t % R);
    int m = (int)(t / R);
    dst[((long)m * C + c) * R + r] = __float2bfloat16(src[idx]);
}

// ======== qkv GEMM: 256x256 tile, BK=64, 4-phase, counted-vmcnt pipeline ========
// C[8192][3072] = A[8192][1024] * BT[3072][1024]^T, fused QKV epilogue.
// 8 waves (2M x 4N), per-wave 128x64. LDS 128 KiB: A/B x 2buf x 2half x [128][64].
// One vmcnt(0)+barrier per K-tile; stages of tile t+1 issued during tile t's
// phases target the other buffer (no per-phase barriers needed).
// Swizzle: granule ^= (row&7) on stage-source and ds_read (both sides).
__global__ __launch_bounds__(512, 2)
void qkv_gemm8(const __hip_bfloat16* __restrict__ A,
               const __hip_bfloat16* __restrict__ BT,
               const float* __restrict__ b0,
               const float* __restrict__ b1,
               const float* __restrict__ b2,
               __hip_bfloat16* __restrict__ Qo,
               __hip_bfloat16* __restrict__ Ko,
               __hip_bfloat16* __restrict__ Vto) {
    __shared__ __align__(16) char lds[131072];
    // A: buf b at b*32768, half h at +h*16384; B: +65536 same structure.
    int tid = threadIdx.x;
    int wid = tid >> 6, lane = tid & 63;
    int lr = lane & 15, lg = lane >> 4;
    int wr = wid >> 2, wc = wid & 3;

    // bijective XCD swizzle over 384 blocks (384 % 8 == 0)
    int bid = blockIdx.x;
    int wg = (bid & 7) * 48 + (bid >> 3);
    int mtile = wg / 12, ntile = wg % 12;

    const int g0 = (lg ^ (lr & 7)) * 16;   // swizzled granule byte-offset, kh=0
    const int g1 = g0 ^ 64;                // kh=1 (granule+4)
    const int arow_off = wr * 16384 + lr * 128;
    const int brow_off = 65536 + (wc >> 1) * 16384 + ((wc & 1) * 64 + lr) * 128;

    const int srow = tid >> 3;
    const int sg = tid & 7;
    const int AR0 = mtile * 256, BR0 = ntile * 256;

    auto stageh = [&](const __hip_bfloat16* gbase, int grow0, int kc, int lbase) {
#pragma unroll
        for (int is = 0; is < 2; ++is) {
            int row = is * 64 + srow;
            int gs = sg ^ (row & 7);
            gload_lds16(gbase + (long)(grow0 + row) * DM + kc + gs * 8,
                        lds + lbase + is * 8192 + wid * 1024);
        }
    };

    f32x4 acc[8][4] = {};
    bf16x8 bfr[4][2];

    // prologue: stage K-tile 0 into buf 0
    stageh(A,  AR0,       0, 0);
    stageh(A,  AR0 + 128, 0, 16384);
    stageh(BT, BR0,       0, 65536);
    stageh(BT, BR0 + 128, 0, 65536 + 16384);

    for (int kt = 0; kt < 16; ++kt) {
        const int cb = (kt & 1) * 32768;
        const int nb = cb ^ 32768;
        const int kc = (kt + 1) * 64;
        // ---- tile boundary: my stages landed -> everyone's landed ----
        asm volatile("s_waitcnt vmcnt(0)" ::: "memory");
        __builtin_amdgcn_s_barrier();
        __builtin_amdgcn_sched_barrier(0);
        // ---- phase 0: B-frags(8) + A m0,m1(4); stage A-half0 of t+1 ----
        {
#pragma unroll
            for (int n = 0; n < 4; ++n) {
                bfr[n][0] = *(const bf16x8*)(lds + cb + brow_off + n * 2048 + g0);
                bfr[n][1] = *(const bf16x8*)(lds + cb + brow_off + n * 2048 + g1);
            }
            bf16x8 a00 = *(const bf16x8*)(lds + cb + arow_off + 0 * 2048 + g0);
            bf16x8 a01 = *(const bf16x8*)(lds + cb + arow_off + 0 * 2048 + g1);
            bf16x8 a10 = *(const bf16x8*)(lds + cb + arow_off + 1 * 2048 + g0);
            bf16x8 a11 = *(const bf16x8*)(lds + cb + arow_off + 1 * 2048 + g1);
            if (kt < 15) stageh(A, AR0, kc, nb);
            asm volatile("s_waitcnt lgkmcnt(0)" ::: "memory");
            __builtin_amdgcn_sched_barrier(0);
            __builtin_amdgcn_s_setprio(1);
#pragma unroll
            for (int n = 0; n < 4; ++n) {
                acc[0][n] = MFMA(a00, bfr[n][0], acc[0][n]);
                acc[0][n] = MFMA(a01, bfr[n][1], acc[0][n]);
                acc[1][n] = MFMA(a10, bfr[n][0], acc[1][n]);
                acc[1][n] = MFMA(a11, bfr[n][1], acc[1][n]);
            }
            __builtin_amdgcn_s_setprio(0);
        }
        // ---- phases 1..3: A m2p,m2p+1; stage A-h1/B-h0/B-h1 of t+1 ----
#pragma unroll
        for (int p = 1; p < 4; ++p) {
            bf16x8 a00 = *(const bf16x8*)(lds + cb + arow_off + (2*p)   * 2048 + g0);
            bf16x8 a01 = *(const bf16x8*)(lds + cb + arow_off + (2*p)   * 2048 + g1);
            bf16x8 a10 = *(const bf16x8*)(lds + cb + arow_off + (2*p+1) * 2048 + g0);
            bf16x8 a11 = *(const bf16x8*)(lds + cb + arow_off + (2*p+1) * 2048 + g1);
            if (kt < 15) {
                if (p == 1) stageh(A,  AR0 + 128, kc, nb + 16384);
                if (p == 2) stageh(BT, BR0,       kc, nb + 65536);
                if (p == 3) stageh(BT, BR0 + 128, kc, nb + 65536 + 16384);
            }
            asm volatile("s_waitcnt lgkmcnt(0)" ::: "memory");
            __builtin_amdgcn_sched_barrier(0);
            __builtin_amdgcn_s_setprio(1);
#pragma unroll
            for (int n = 0; n < 4; ++n) {
                acc[2*p][n]   = MFMA(a00, bfr[n][0], acc[2*p][n]);
                acc[2*p][n]   = MFMA(a01, bfr[n][1], acc[2*p][n]);
                acc[2*p+1][n] = MFMA(a10, bfr[n][0], acc[2*p+1][n]);
                acc[2*p+1][n] = MFMA(a11, bfr[n][1], acc[2*p+1][n]);
            }
            __builtin_amdgcn_s_setprio(0);
        }
    }

    // ---- epilogue ----
    int z = ntile >> 2;                              // 0:Q 1:K 2:V (uniform)
    const float* bias = (z == 0) ? b0 : (z == 1) ? b1 : b2;
    int cb0 = (ntile & 3) * 256 + wc * 64;
#pragma unroll
    for (int n = 0; n < 4; ++n) {
        int hc = cb0 + n * 16 + lr;                  // h*64+e within 1024
        int h = hc >> 6, e = hc & 63;
        float bb = bias[hc];
#pragma unroll
        for (int m = 0; m < 8; ++m) {
            int row0 = mtile * 256 + wr * 128 + m * 16 + lg * 4;
            int b = row0 >> 11, s0 = row0 & 2047;
            if (z == 0) {
#pragma unroll
                for (int r = 0; r < 4; ++r)
                    Qo[(((long)b * NH + h) * SEQ + s0 + r) * HD + e] =
                        __float2bfloat16((acc[m][n][r] + bb) * QSCALE);
            } else if (z == 1) {
#pragma unroll
                for (int r = 0; r < 4; ++r)
                    Ko[(((long)b * NH + h) * SEQ + s0 + r) * HD + e] =
                        __float2bfloat16(acc[m][n][r] + bb);
            } else {
                ushort4 s4;
                s4.x = __bfloat16_as_ushort(__float2bfloat16(acc[m][n][0] + bb));
                s4.y = __bfloat16_as_ushort(__float2bfloat16(acc[m][n][1] + bb));
                s4.z = __bfloat16_as_ushort(__float2bfloat16(acc[m][n][2] + bb));
                s4.w = __bfloat16_as_ushort(__float2bfloat16(acc[m][n][3] + bb));
                *reinterpret_cast<ushort4*>(
                    Vto + ((long)(b * NH + h) * HD + e) * SEQ + s0) = s4;
            }
        }
    }
}

// ---------------- out projection GEMM (proven 128x128 m97 structure) ----------------
__global__ __launch_bounds__(256)
void out_gemm(const __hip_bfloat16* __restrict__ A,
              const __hip_bfloat16* __restrict__ BT,
              const float* __restrict__ b0,
              float* __restrict__ Fo) {
    __shared__ __align__(16) char smem[2][16384];   // [buf][A:0..8191 | B:8192..16383]
    int tid = threadIdx.x;
    int w = tid >> 6, l = tid & 63;
    int wr = w >> 1, wc = w & 1;
    int lr = l & 15, lg = l >> 4;
    int mtile = blockIdx.x, ntile = blockIdx.y;

    const __hip_bfloat16* Ab = A  + (long)mtile * 128 * DM;
    const __hip_bfloat16* Bb = BT + (long)ntile * 128 * DM;

    const int srow0 = tid >> 2;
    const int srow1 = 64 + srow0;
    const int g0 = (tid & 3) ^ ((srow0 >> 1) & 3);

    int aoff[4], boff[4];
#pragma unroll
    for (int m = 0; m < 4; ++m) {
        int ra = wr * 64 + m * 16 + lr;
        aoff[m] = ra * 64 + ((lg ^ ((ra >> 1) & 3)) * 16);
        int rb = wc * 64 + m * 16 + lr;
        boff[m] = 8192 + rb * 64 + ((lg ^ ((rb >> 1) & 3)) * 16);
    }

    f32x4 acc[4][4] = {};

    {
        char* base = smem[0] + w * 1024;
        gload_lds16(Ab + (long)srow0 * DM + g0 * 8, base);
        gload_lds16(Ab + (long)srow1 * DM + g0 * 8, base + 4096);
        gload_lds16(Bb + (long)srow0 * DM + g0 * 8, base + 8192);
        gload_lds16(Bb + (long)srow1 * DM + g0 * 8, base + 12288);
    }
    __syncthreads();

    int cur = 0;
    for (int kt = 0; kt < 32; ++kt) {
        if (kt != 31) {
            int k0 = (kt + 1) * 32;
            char* base = smem[cur ^ 1] + w * 1024;
            gload_lds16(Ab + (long)srow0 * DM + k0 + g0 * 8, base);
            gload_lds16(Ab + (long)srow1 * DM + k0 + g0 * 8, base + 4096);
            gload_lds16(Bb + (long)srow0 * DM + k0 + g0 * 8, base + 8192);
            gload_lds16(Bb + (long)srow1 * DM + k0 + g0 * 8, base + 12288);
        }
        bf16x8 af[4], bf[4];
#pragma unroll
        for (int m = 0; m < 4; ++m)
            af[m] = *reinterpret_cast<const bf16x8*>(smem[cur] + aoff[m]);
#pragma unroll
        for (int n = 0; n < 4; ++n)
            bf[n] = *reinterpret_cast<const bf16x8*>(smem[cur] + boff[n]);
#pragma unroll
        for (int m = 0; m < 4; ++m)
#pragma unroll
            for (int n = 0; n < 4; ++n)
                acc[m][n] = MFMA(af[m], bf[n], acc[m][n]);
        __syncthreads();
        cur ^= 1;
    }

#pragma unroll
    for (int n = 0; n < 4; ++n) {
        int col = ntile * 128 + wc * 64 + n * 16 + lr;
        float bb = b0[col];
#pragma unroll
        for (int m = 0; m < 4; ++m) {
            long row0 = mtile * 128 + wr * 64 + m * 16 + lg * 4;
#pragma unroll
            for (int r = 0; r < 4; ++r)
                Fo[(row0 + r) * DM + col] = acc[m][n][r] + bb;
        }
    }
}

// ---------------- helpers for flash ----------------
static __device__ __forceinline__ unsigned pkbf(float a, float b) {
    __hip_bfloat162 h = __float22bfloat162_rn(float2{a, b});  // a -> low 16
    union { __hip_bfloat162 h2; unsigned u; } u_; u_.h2 = h;
    return u_.u;
}
static __device__ __forceinline__ bf16x8 make_pb(unsigned w0, unsigned w1,
                                                 unsigned w2, unsigned w3) {
    union { unsigned u[4]; bf16x8 v; } u_;
    u_.u[0] = w0; u_.u[1] = w1; u_.u[2] = w2; u_.u[3] = w3;
    return u_.v;
}
// v_permlane32_swap: r[0] = concat(a_lo, b_lo), r[1] = concat(a_hi, b_hi)
static __device__ __forceinline__ i32x2 pl32swap(unsigned a, unsigned b) {
    return __builtin_amdgcn_permlane32_swap((int)a, (int)b, false, false);
}
static __device__ __forceinline__ float xmax32(float x) {
    i32x2 r = pl32swap(__float_as_uint(x), __float_as_uint(x));
    return fmaxf(__uint_as_float((unsigned)r[0]), __uint_as_float((unsigned)r[1]));
}
static __device__ __forceinline__ float xsum32(float x) {
    i32x2 r = pl32swap(__float_as_uint(x), __float_as_uint(x));
    return __uint_as_float((unsigned)r[0]) + __uint_as_float((unsigned)r[1]);
}

// One kv-tile of one chain: QK^T (swapped), online softmax (exp2 domain,
// defer-max), P->bf16 B-frags via permlane32_swap, PV accumulate.
template<bool MASKED>
static __device__ __forceinline__ void attn_tile(
    const bf16x8* kf, const bf16x8* qf,
    bf16x8 v00, bf16x8 v10, bf16x8 v01, bf16x8 v11,
    int lo5, int hi,
    f32x16& o0, f32x16& o1, float& m, float& lsum) {
    f32x16 st = {};
    __builtin_amdgcn_s_setprio(1);
#pragma unroll
    for (int kd = 0; kd < 4; ++kd) st = MFMA32(kf[kd], qf[kd], st);
    __builtin_amdgcn_s_setprio(0);
    if (MASKED) {
#pragma unroll
        for (int r = 0; r < 16; ++r) {
            int kvloc = (r & 3) + 8 * (r >> 2) + 4 * hi;
            st[r] = (kvloc > lo5) ? -INFINITY : st[r];
        }
    }
    // tree max over 16 regs, then cross-half via permlane
    float t0 = fmaxf(st[0], st[1]),   t1 = fmaxf(st[2], st[3]);
    float t2 = fmaxf(st[4], st[5]),   t3 = fmaxf(st[6], st[7]);
    float t4 = fmaxf(st[8], st[9]),   t5 = fmaxf(st[10], st[11]);
    float t6 = fmaxf(st[12], st[13]), t7 = fmaxf(st[14], st[15]);
    t0 = fmaxf(t0, t1); t2 = fmaxf(t2, t3); t4 = fmaxf(t4, t5); t6 = fmaxf(t6, t7);
    float tm = xmax32(fmaxf(fmaxf(t0, t2), fmaxf(t4, t6)));
    if (!__all(tm <= m + 11.0f)) {          // defer-max: p bounded by 2^11
        float mnew = fmaxf(m, tm);
        float fac = __builtin_amdgcn_exp2f(m - mnew);
        lsum *= fac;
#pragma unroll
        for (int r = 0; r < 16; ++r) { o0[r] *= fac; o1[r] *= fac; }
        m = mnew;
    }
    float p[16];
#pragma unroll
    for (int r = 0; r < 16; ++r) p[r] = __builtin_amdgcn_exp2f(st[r] - m);
    float s0 = (p[0] + p[1]) + (p[2] + p[3]);
    float s1 = (p[4] + p[5]) + (p[6] + p[7]);
    float s2 = (p[8] + p[9]) + (p[10] + p[11]);
    float s3 = (p[12] + p[13]) + (p[14] + p[15]);
    lsum += xsum32((s0 + s1) + (s2 + s3));

    unsigned pk0 = pkbf(p[0],  p[1]),  pk1 = pkbf(p[2],  p[3]);
    unsigned pk2 = pkbf(p[4],  p[5]),  pk3 = pkbf(p[6],  p[7]);
    unsigned pk4 = pkbf(p[8],  p[9]),  pk5 = pkbf(p[10], p[11]);
    unsigned pk6 = pkbf(p[12], p[13]), pk7 = pkbf(p[14], p[15]);
    i32x2 s02 = pl32swap(pk0, pk2);
    i32x2 s13 = pl32swap(pk1, pk3);
    i32x2 s46 = pl32swap(pk4, pk6);
    i32x2 s57 = pl32swap(pk5, pk7);
    bf16x8 pb0 = make_pb((unsigned)s02[0], (unsigned)s13[0],
                         (unsigned)s02[1], (unsigned)s13[1]);
    bf16x8 pb1 = make_pb((unsigned)s46[0], (unsigned)s57[0],
                         (unsigned)s46[1], (unsigned)s57[1]);

    __builtin_amdgcn_s_setprio(1);
    o0 = MFMA32(v00, pb0, o0);
    o1 = MFMA32(v10, pb0, o1);
    o0 = MFMA32(v01, pb1, o0);
    o1 = MFMA32(v11, pb1, o1);
    __builtin_amdgcn_s_setprio(0);
}

// ---------------- flash attention (causal, paired antidiagonal waves) ----------------
// Q (pre-scaled by QSCALE), K: [B,H,S,HD]; Vt: [B,H,HD,S]; O: [B*S][DM] (col h*64+d)
__global__ __launch_bounds__(256)
void flash_attn(const __hip_bfloat16* __restrict__ Q,
                const __hip_bfloat16* __restrict__ K,
                const __hip_bfloat16* __restrict__ Vt,
                __hip_bfloat16* __restrict__ O) {
    int bh = blockIdx.x;                       // x=bh: same-head blocks share XCD
    int w  = threadIdx.x >> 6, l = threadIdx.x & 63;
    int lo5 = l & 31, hi = l >> 5;
    int pair = blockIdx.y * 4 + w;             // 0..31
    int jA = pair, jB = 63 - pair;
    int q0A = jA * 32, q0B = jB * 32;

    const __hip_bfloat16* Qh = Q  + (long)bh * SEQ * HD;
    const __hip_bfloat16* Kh = K  + (long)bh * SEQ * HD;
    const __hip_bfloat16* Vh = Vt + (long)bh * HD * SEQ;   // [64][2048]

    bf16x8 qfA[4], qfB[4];
#pragma unroll
    for (int kd = 0; kd < 4; ++kd) {
        qfA[kd] = *reinterpret_cast<const bf16x8*>(
            Qh + (long)(q0A + lo5) * HD + kd * 16 + hi * 8);
        qfB[kd] = *reinterpret_cast<const bf16x8*>(
            Qh + (long)(q0B + lo5) * HD + kd * 16 + hi * 8);
    }

    f32x16 oA0 = {}, oA1 = {}, oB0 = {}, oB1 = {};
    float mA = -INFINITY, lsA = 0.f, mB = -INFINITY, lsB = 0.f;

    bf16x8 kf[4], kn[4];
#pragma unroll
    for (int kd = 0; kd < 4; ++kd)
        kf[kd] = *reinterpret_cast<const bf16x8*>(
            Kh + (long)(lo5) * HD + kd * 16 + hi * 8);

#define LOADK(T, DST)                                                      \
    _Pragma("unroll")                                                      \
    for (int kd = 0; kd < 4; ++kd)                                         \
        DST[kd] = *reinterpret_cast<const bf16x8*>(                        \
            Kh + (long)((T) * 32 + lo5) * HD + kd * 16 + hi * 8);

#define LOADV(KV0)                                                         \
    bf16x8 v00 = *reinterpret_cast<const bf16x8*>(                         \
        Vh + (long)(lo5) * SEQ + (KV0) + hi * 8);                          \
    bf16x8 v10 = *reinterpret_cast<const bf16x8*>(                         \
        Vh + (long)(32 + lo5) * SEQ + (KV0) + hi * 8);                     \
    bf16x8 v01 = *reinterpret_cast<const bf16x8*>(                         \
        Vh + (long)(lo5) * SEQ + (KV0) + 16 + hi * 8);                     \
    bf16x8 v11 = *reinterpret_cast<const bf16x8*>(                         \
        Vh + (long)(32 + lo5) * SEQ + (KV0) + 16 + hi * 8);

    for (int t = 0; t < jA; ++t) {
        LOADK(t + 1, kn);
        LOADV(t * 32);
        attn_tile<false>(kf, qfB, v00, v10, v01, v11, lo5, hi, oB0, oB1, mB, lsB);
        attn_tile<false>(kf, qfA, v00, v10, v01, v11, lo5, hi, oA0, oA1, mA, lsA);
        kf[0] = kn[0]; kf[1] = kn[1]; kf[2] = kn[2]; kf[3] = kn[3];
    }
    {   // t = jA: A's diagonal
        LOADK(jA + 1, kn);
        LOADV(jA * 32);
        attn_tile<true >(kf, qfA, v00, v10, v01, v11, lo5, hi, oA0, oA1, mA, lsA);
        attn_tile<false>(kf, qfB, v00, v10, v01, v11, lo5, hi, oB0, oB1, mB, lsB);
        kf[0] = kn[0]; kf[1] = kn[1]; kf[2] = kn[2]; kf[3] = kn[3];
    }
    for (int t = jA + 1; t < jB; ++t) {
        LOADK(t + 1, kn);
        LOADV(t * 32);
        attn_tile<false>(kf, qfB, v00, v10, v01, v11, lo5, hi, oB0, oB1, mB, lsB);
        kf[0] = kn[0]; kf[1] = kn[1]; kf[2] = kn[2]; kf[3] = kn[3];
    }
    {   // t = jB: B's diagonal
        LOADV(jB * 32);
        attn_tile<true >(kf, qfB, v00, v10, v01, v11, lo5, hi, oB0, oB1, mB, lsB);
    }
#undef LOADK
#undef LOADV

    int b = bh >> 4, h = bh & 15;
#pragma unroll
    for (int c = 0; c < 2; ++c) {
        int q0 = c ? q0B : q0A;
        const f32x16& o0 = c ? oB0 : oA0;
        const f32x16& o1 = c ? oB1 : oA1;
        float inv = 1.0f / (c ? lsB : lsA);
        __hip_bfloat16* orow = O + ((long)b * SEQ + q0 + lo5) * DM + h * HD;
#pragma unroll
        for (int nd = 0; nd < 2; ++nd) {
#pragma unroll
            for (int rg = 0; rg < 4; ++rg) {
                ushort4 s4;
                float a0 = (nd ? o1[rg * 4 + 0] : o0[rg * 4 + 0]) * inv;
                float a1 = (nd ? o1[rg * 4 + 1] : o0[rg * 4 + 1]) * inv;
                float a2 = (nd ? o1[rg * 4 + 2] : o0[rg * 4 + 2]) * inv;
                float a3 = (nd ? o1[rg * 4 + 3] : o0[rg * 4 + 3]) * inv;
                s4.x = __bfloat16_as_ushort(__float2bfloat16(a0));
                s4.y = __bfloat16_as_ushort(__float2bfloat16(a1));
                s4.z = __bfloat16_as_ushort(__float2bfloat16(a2));
                s4.w = __bfloat16_as_ushort(__float2bfloat16(a3));
                *reinterpret_cast<ushort4*>(orow + nd * 32 + rg * 8 + hi * 4) = s4;
            }
        }
    }
}

extern "C" void kernel_launch(void* const* d_in, const int* in_sizes, int n_in,
                              void* d_out, int out_size, void* d_ws, size_t ws_size,
                              hipStream_t stream) {
    const float* x  = (const float*)d_in[0];
    const float* Wq = (const float*)d_in[1];
    const float* bq = (const float*)d_in[2];
    const float* Wk = (const float*)d_in[3];
    const float* bk = (const float*)d_in[4];
    const float* Wv = (const float*)d_in[5];
    const float* bv = (const float*)d_in[6];
    const float* Wp = (const float*)d_in[7];
    const float* bp = (const float*)d_in[8];
    float* out = (float*)d_out;

    char* ws = (char*)d_ws;
    const long XE = (long)NB * SEQ * DM;                 // 8,388,608
    const long QKV_ELEMS = (long)NB * NH * SEQ * HD;     // 8,388,608
    __hip_bfloat16* xb   = (__hip_bfloat16*)ws; ws += XE * 2;
    __hip_bfloat16* Qws  = (__hip_bfloat16*)ws; ws += QKV_ELEMS * 2;
    __hip_bfloat16* Kws  = (__hip_bfloat16*)ws; ws += QKV_ELEMS * 2;
    __hip_bfloat16* Vtws = (__hip_bfloat16*)ws; ws += QKV_ELEMS * 2;
    __hip_bfloat16* Ows  = (__hip_bfloat16*)ws; ws += QKV_ELEMS * 2;
    // fused WT[3072][1024]: rows 0-1023 = Wq^T, 1024-2047 = Wk^T, 2048-3071 = Wv^T
    __hip_bfloat16* wqt  = (__hip_bfloat16*)ws; ws += (long)NH * DM * HD * 2;
    __hip_bfloat16* wkt  = (__hip_bfloat16*)ws; ws += (long)NH * DM * HD * 2;
    __hip_bfloat16* wvt  = (__hip_bfloat16*)ws; ws += (long)NH * DM * HD * 2;
    __hip_bfloat16* wpt  = (__hip_bfloat16*)ws; ws += (long)DM * DM * 2;

    cast_f32_bf16<<<(int)(XE / 4 / 256), 256, 0, stream>>>(x, xb, XE);

    {
        long tot = (long)NH * DM * HD;
        int blks = (int)((tot + 255) / 256);
        transpose_cast_k<<<blks, 256, 0, stream>>>(Wq, wqt, NH, DM, HD);
        transpose_cast_k<<<blks, 256, 0, stream>>>(Wk, wkt, NH, DM, HD);
        transpose_cast_k<<<blks, 256, 0, stream>>>(Wv, wvt, NH, DM, HD);
        long tot2 = (long)DM * DM;
        transpose_cast_k<<<(int)((tot2 + 255) / 256), 256, 0, stream>>>(Wp, wpt, 1, DM, DM);
    }

    qkv_gemm8<<<384, 512, 0, stream>>>(
        xb, wqt, bq, bk, bv, Qws, Kws, Vtws);

    flash_attn<<<dim3(64, 8), 256, 0, stream>>>(Qws, Kws, Vtws, Ows);

    out_gemm<<<dim3(64, 8), 256, 0, stream>>>(Ows, wpt, bp, out);
}